// Round 5
// baseline (268.478 us; speedup 1.0000x reference)
//
#include <hip/hip_runtime.h>
#include <hip/hip_bf16.h>

using f32x4  = __attribute__((ext_vector_type(4))) float;
using f32x16 = __attribute__((ext_vector_type(16))) float;
using short8 = __attribute__((ext_vector_type(8))) short;
using us8    = __attribute__((ext_vector_type(8))) unsigned short;
using us4    = __attribute__((ext_vector_type(4))) unsigned short;
using fl4    = __attribute__((ext_vector_type(4))) float;

__device__ __forceinline__ unsigned short f2bf(float f){
    unsigned u = __builtin_bit_cast(unsigned, f);
    u += 0x7FFF + ((u >> 16) & 1);
    return (unsigned short)(u >> 16);
}

__device__ __forceinline__ unsigned cvtpk_bf16(float lo, float hi){
    unsigned r;
    asm volatile("v_cvt_pk_bf16_f32 %0, %1, %2" : "=v"(r) : "v"(lo), "v"(hi));
    return r;
}

// swaps a's lanes 32-63 with b's lanes 0-31
__device__ __forceinline__ void pl32swap(unsigned &a, unsigned &b){
    asm volatile("v_permlane32_swap_b32 %0, %1" : "+v"(a), "+v"(b));
}

__device__ __forceinline__ void gload16(const unsigned short* g, unsigned short* l) {
    __builtin_amdgcn_global_load_lds(
        (const __attribute__((address_space(1))) unsigned int*)g,
        (__attribute__((address_space(3))) unsigned int*)l, 16, 0, 0);
}

// ---------------- fp32 -> bf16 conversion ----------------
__global__ __launch_bounds__(256)
void conv_bf16(const float* __restrict__ s0, const float* __restrict__ s1, const float* __restrict__ s2,
               const float* __restrict__ s3, const float* __restrict__ s4, const float* __restrict__ s5,
               const float* __restrict__ s6,
               unsigned short* __restrict__ d0, unsigned short* __restrict__ d1, unsigned short* __restrict__ d2,
               unsigned short* __restrict__ d3, unsigned short* __restrict__ d4, unsigned short* __restrict__ d5,
               unsigned short* __restrict__ d6,
               int nbig4, int nsml4)
{
    const int z = blockIdx.z;
    const float* s = (z==0)?s0:(z==1)?s1:(z==2)?s2:(z==3)?s3:(z==4)?s4:(z==5)?s5:s6;
    unsigned short* d = (z==0)?d0:(z==1)?d1:(z==2)?d2:(z==3)?d3:(z==4)?d4:(z==5)?d5:d6;
    const int n4 = (z < 3) ? nbig4 : nsml4;
    const int stride = gridDim.x * blockDim.x;
    for (int i = blockIdx.x * blockDim.x + threadIdx.x; i < n4; i += stride) {
        fl4 v = ((const fl4*)s)[i];
        us4 o = { f2bf(v[0]), f2bf(v[1]), f2bf(v[2]), f2bf(v[3]) };
        ((us4*)d)[i] = o;
    }
}

// ---------------- bf16 GEMM, 2-phase counted-vmcnt prefetch ----------------
template<bool OBF16>
__global__ __launch_bounds__(256, 2)
void gemm_bf16(const unsigned short* __restrict__ A0, const unsigned short* __restrict__ A1,
               const unsigned short* __restrict__ A2,
               const unsigned short* __restrict__ W0, const unsigned short* __restrict__ W1,
               const unsigned short* __restrict__ W2,
               const float* __restrict__ B0, const float* __restrict__ B1, const float* __restrict__ B2,
               void* __restrict__ O0, void* __restrict__ O1, void* __restrict__ O2,
               int M, int N, int K)
{
    const int z = blockIdx.z;
    const unsigned short* Ap = (z==0)?A0:(z==1)?A1:A2;
    const unsigned short* Wp = (z==0)?W0:(z==1)?W1:W2;
    const float* bp = (z==0)?B0:(z==1)?B1:B2;
    void* Op = (z==0)?O0:(z==1)?O1:O2;

    const int tid = threadIdx.x, lane = tid & 63, w = tid >> 6;
    const int wr = w >> 1, wc = w & 1;
    const int l15 = lane & 15, l4 = lane >> 4;
    const int bm = blockIdx.y, bn = blockIdx.x;

    __shared__ unsigned short As[2][128 * 64];
    __shared__ unsigned short Bs[2][128 * 64];

    f32x4 acc[4][4];
    #pragma unroll
    for (int i = 0; i < 4; i++)
        #pragma unroll
        for (int j = 0; j < 4; j++) acc[i][j] = (f32x4){0.f, 0.f, 0.f, 0.f};

    const int KT = K >> 6;
    const int srow = lane >> 3;
    const int scol = (lane & 7) * 8;

    auto stage = [&](int buf, int kt) {
        #pragma unroll
        for (int i = 0; i < 4; i++) {
            const int chunk = w * 4 + i;
            const int row = chunk * 8 + srow;
            gload16(Ap + (size_t)(bm * 128 + row) * K + kt * 64 + scol, &As[buf][chunk * 512]);
            gload16(Wp + (size_t)(bn * 128 + row) * K + kt * 64 + scol, &Bs[buf][chunk * 512]);
        }
    };

    stage(0, 0);
    int cur = 0;
    for (int kt = 0; kt < KT; ++kt) {
        if (kt + 1 < KT) {
            stage(cur ^ 1, kt + 1);
            asm volatile("s_waitcnt vmcnt(8)" ::: "memory");
        } else {
            asm volatile("s_waitcnt vmcnt(0)" ::: "memory");
        }
        __builtin_amdgcn_s_barrier();

        short8 af[4][2], bfr[4][2];
        #pragma unroll
        for (int mf = 0; mf < 4; mf++)
            #pragma unroll
            for (int kf = 0; kf < 2; kf++)
                af[mf][kf] = *(const short8*)&As[cur][(wr * 64 + mf * 16 + l15) * 64 + kf * 32 + l4 * 8];
        #pragma unroll
        for (int nf = 0; nf < 4; nf++)
            #pragma unroll
            for (int kf = 0; kf < 2; kf++)
                bfr[nf][kf] = *(const short8*)&Bs[cur][(wc * 64 + nf * 16 + l15) * 64 + kf * 32 + l4 * 8];
        #pragma unroll
        for (int mf = 0; mf < 4; mf++)
            #pragma unroll
            for (int nf = 0; nf < 4; nf++)
                #pragma unroll
                for (int kf = 0; kf < 2; kf++)
                    acc[mf][nf] = __builtin_amdgcn_mfma_f32_16x16x32_bf16(af[mf][kf], bfr[nf][kf], acc[mf][nf], 0, 0, 0);

        __builtin_amdgcn_s_barrier();
        cur ^= 1;
    }

    #pragma unroll
    for (int mf = 0; mf < 4; mf++) {
        int row = bm * 128 + wr * 64 + mf * 16 + l4 * 4;
        #pragma unroll
        for (int nf = 0; nf < 4; nf++) {
            int col = bn * 128 + wc * 64 + nf * 16 + l15;
            float bv = bp[col];
            #pragma unroll
            for (int r = 0; r < 4; r++) {
                float vv = acc[mf][nf][r] + bv;
                if constexpr (OBF16)
                    ((unsigned short*)Op)[(size_t)(row + r) * N + col] = f2bf(vv);
                else
                    ((float*)Op)[(size_t)(row + r) * N + col] = vv;
            }
        }
    }
}

// ---------------- V transpose: Vp [b][s][h*64+d] -> VpT [b][h][d][s] ----------
__global__ __launch_bounds__(256)
void transpose_v(const unsigned short* __restrict__ Vp, unsigned short* __restrict__ VpT)
{
    const int bh = blockIdx.y, b = bh >> 4, h = bh & 15;
    const int s0 = blockIdx.x * 64;
    const int tid = threadIdx.x;
    __shared__ unsigned short T[64 * 64];
    #pragma unroll
    for (int i = 0; i < 2; i++) {
        int cc = i * 256 + tid, r = cc >> 3, c = cc & 7;
        us8 v = *(const us8*)(Vp + (size_t)(b * 2048 + s0 + r) * 1024 + h * 64 + c * 8);
        int off = (r * 128 + c * 16) ^ ((((r & 7) ^ ((r >> 3) & 7))) << 4);
        *(us8*)((char*)T + off) = v;
    }
    __syncthreads();
    #pragma unroll
    for (int i = 0; i < 2; i++) {
        int cc = i * 256 + tid, d = cc >> 3, c = cc & 7;
        us8 o;
        #pragma unroll
        for (int j = 0; j < 8; j++) {
            int s = c * 8 + j;
            int off = (s * 128 + d * 2) ^ ((((s & 7) ^ ((s >> 3) & 7))) << 4);
            o[j] = *(const unsigned short*)((const char*)T + off);
        }
        *(us8*)(VpT + ((size_t)bh * 64 + d) * 2048 + s0 + c * 8) = o;
    }
}

// ---------------- causal flash attention, 32x32 swapped, P in-register -------
// Block = 2 waves x 32 q-rows = 64 q-rows. Paired q-tiles (qt, 31-qt): 33 KV
// tiles of 64 per block. S^T = mfma(K,Q): lane owns q-row (lane&31); softmax
// in-register (1 shfl_xor(32) per reduce); O^T acc -> lane-local rescale;
// P->B-frag via cvt_pk_bf16 + permlane32_swap (no LDS round trip).
__global__ __launch_bounds__(128)
void attn_causal(const unsigned short* __restrict__ Qp,
                 const unsigned short* __restrict__ Kp,
                 const unsigned short* __restrict__ VpT,
                 unsigned short* __restrict__ Ctx)
{
    const int S = 2048, D = 1024;
    const int bh = blockIdx.y, b = bh >> 4, h = bh & 15;
    const int pairIdx = blockIdx.x;               // 0..15
    const int tid = threadIdx.x, w = tid >> 6, lane = tid & 63;
    const int l31 = lane & 31, hi = lane >> 5;

    __shared__ unsigned short Ks[64 * 64];        // [kv][k], row-swizzled
    __shared__ unsigned short Vt[64 * 64];        // [d][kv], row-swizzled

    const float sc = 0.125f * 1.44269504088896f;  // 1/sqrt(64) * log2(e)

    for (int phase = 0; phase < 2; ++phase) {
        const int qt = (phase == 0) ? pairIdx : 31 - pairIdx;
        const int nt = qt + 1;
        const int qrow = qt * 64 + w * 32 + l31;  // this lane's q-row

        short8 qf[4];
        #pragma unroll
        for (int ks = 0; ks < 4; ks++)
            qf[ks] = *(const short8*)(Qp + (size_t)(b * S + qrow) * D + h * 64 + ks * 16 + hi * 8);

        float mrow = -3.0e38f, lrow = 0.f;
        f32x16 oacc[2];
        #pragma unroll
        for (int dh = 0; dh < 2; dh++)
            #pragma unroll
            for (int r = 0; r < 16; r++) oacc[dh][r] = 0.f;

        us8 krg[4], vtrg[4];
        #pragma unroll
        for (int i = 0; i < 4; i++) {
            int cc = i * 128 + tid, r = cc >> 3, c = cc & 7;
            krg[i]  = *(const us8*)(Kp  + (size_t)(b * S + r) * D + h * 64 + c * 8);
            vtrg[i] = *(const us8*)(VpT + ((size_t)bh * 64 + r) * 2048 + c * 8);
        }

        for (int t = 0; t < nt; ++t) {
            __syncthreads();   // previous tile fully consumed
            #pragma unroll
            for (int i = 0; i < 4; i++) {
                int cc = i * 128 + tid, r = cc >> 3, c = cc & 7;
                int off = (r * 128 + c * 16) ^ ((r & 7) << 4);
                *(us8*)((char*)Ks + off) = krg[i];
                *(us8*)((char*)Vt + off) = vtrg[i];
            }
            __syncthreads();   // published

            if (t + 1 < nt) {
                #pragma unroll
                for (int i = 0; i < 4; i++) {
                    int cc = i * 128 + tid, r = cc >> 3, c = cc & 7;
                    krg[i]  = *(const us8*)(Kp  + (size_t)(b * S + (t + 1) * 64 + r) * D + h * 64 + c * 8);
                    vtrg[i] = *(const us8*)(VpT + ((size_t)bh * 64 + r) * 2048 + (t + 1) * 64 + c * 8);
                }
            }

            // S^T[kv][q] = K @ Q^T ; lane: q = l31, holds kv pattern (r&3)+8*(r>>2)+4*hi
            f32x16 sacc[2];
            #pragma unroll
            for (int kvh = 0; kvh < 2; kvh++)
                #pragma unroll
                for (int r = 0; r < 16; r++) sacc[kvh][r] = 0.f;
            #pragma unroll
            for (int kvh = 0; kvh < 2; kvh++)
                #pragma unroll
                for (int ks = 0; ks < 4; ks++) {
                    int row = kvh * 32 + l31;
                    int off = (row * 128 + ks * 32 + hi * 16) ^ ((l31 & 7) << 4);
                    short8 kfrag = *(const short8*)((const char*)Ks + off);
                    sacc[kvh] = __builtin_amdgcn_mfma_f32_32x32x16_bf16(kfrag, qf[ks], sacc[kvh], 0, 0, 0);
                }

            // scale + mask -> pf
            float pf[2][16];
            const bool domask = (t == nt - 1);
            #pragma unroll
            for (int kvh = 0; kvh < 2; kvh++)
                #pragma unroll
                for (int r = 0; r < 16; r++) {
                    float x = sacc[kvh][r] * sc;
                    if (domask) {
                        int kv = t * 64 + kvh * 32 + (r & 3) + 8 * (r >> 2) + 4 * hi;
                        if (kv > qrow) x = -3.0e38f;
                    }
                    pf[kvh][r] = x;
                }

            // row softmax: tree over this lane's 32 values + xor-32 with partner
            float pm = -3.0e38f;
            #pragma unroll
            for (int kvh = 0; kvh < 2; kvh++)
                #pragma unroll
                for (int r = 0; r < 16; r++) pm = fmaxf(pm, pf[kvh][r]);
            pm = fmaxf(pm, __shfl_xor(pm, 32));
            float mn = fmaxf(mrow, pm);
            float fs = exp2f(mrow - mn);
            float ps = 0.f;
            #pragma unroll
            for (int kvh = 0; kvh < 2; kvh++)
                #pragma unroll
                for (int r = 0; r < 16; r++) {
                    float e = exp2f(pf[kvh][r] - mn);
                    pf[kvh][r] = e;
                    ps += e;
                }
            ps += __shfl_xor(ps, 32);
            lrow = lrow * fs + ps;
            mrow = mn;
            #pragma unroll
            for (int dh = 0; dh < 2; dh++)
                #pragma unroll
                for (int r = 0; r < 16; r++) oacc[dh][r] *= fs;   // q lane-local

            // P -> bf16 B-frags via cvt_pk + permlane32_swap, then O^T += V^T P^T
            #pragma unroll
            for (int kvh = 0; kvh < 2; kvh++) {
                unsigned w00 = cvtpk_bf16(pf[kvh][0],  pf[kvh][1]);
                unsigned w01 = cvtpk_bf16(pf[kvh][2],  pf[kvh][3]);
                unsigned w10 = cvtpk_bf16(pf[kvh][4],  pf[kvh][5]);
                unsigned w11 = cvtpk_bf16(pf[kvh][6],  pf[kvh][7]);
                unsigned w20 = cvtpk_bf16(pf[kvh][8],  pf[kvh][9]);
                unsigned w21 = cvtpk_bf16(pf[kvh][10], pf[kvh][11]);
                unsigned w30 = cvtpk_bf16(pf[kvh][12], pf[kvh][13]);
                unsigned w31 = cvtpk_bf16(pf[kvh][14], pf[kvh][15]);
                pl32swap(w00, w10);   // stepA words 0,2
                pl32swap(w01, w11);   // stepA words 1,3
                pl32swap(w20, w30);   // stepB words 0,2
                pl32swap(w21, w31);   // stepB words 1,3
                unsigned stepA[4] = { w00, w01, w10, w11 };
                unsigned stepB[4] = { w20, w21, w30, w31 };
                short8 bA = __builtin_bit_cast(short8, *(const us8*)stepA);
                short8 bB = __builtin_bit_cast(short8, *(const us8*)stepB);
                #pragma unroll
                for (int dh = 0; dh < 2; dh++) {
                    int row = dh * 32 + l31;
                    int offA = (row * 128 + kvh * 64 + hi * 16) ^ ((l31 & 7) << 4);
                    short8 vA = *(const short8*)((const char*)Vt + offA);
                    oacc[dh] = __builtin_amdgcn_mfma_f32_32x32x16_bf16(vA, bA, oacc[dh], 0, 0, 0);
                    int offB = offA ^ 32;   // +32 bytes = step*16 bf16 (bit5 not in swizzle)
                    short8 vB = *(const short8*)((const char*)Vt + offB);
                    oacc[dh] = __builtin_amdgcn_mfma_f32_32x32x16_bf16(vB, bB, oacc[dh], 0, 0, 0);
                }
            }
        }

        // epilogue: O^T reg r -> d_local = (r&3) + 8*(r>>2) + 4*hi, q = l31
        float invl = 1.0f / lrow;
        #pragma unroll
        for (int dh = 0; dh < 2; dh++)
            #pragma unroll
            for (int tq = 0; tq < 4; tq++) {
                us4 o = { f2bf(oacc[dh][4*tq+0] * invl), f2bf(oacc[dh][4*tq+1] * invl),
                          f2bf(oacc[dh][4*tq+2] * invl), f2bf(oacc[dh][4*tq+3] * invl) };
                int d = dh * 32 + tq * 8 + hi * 4;
                *(us4*)(Ctx + (size_t)(b * S + qrow) * D + h * 64 + d) = o;
            }
    }
}

extern "C" void kernel_launch(void* const* d_in, const int* in_sizes, int n_in,
                              void* d_out, int out_size, void* d_ws, size_t ws_size,
                              hipStream_t stream)
{
    const float* q  = (const float*)d_in[0];
    const float* k  = (const float*)d_in[1];
    const float* v  = (const float*)d_in[2];
    const float* Wq = (const float*)d_in[3];
    const float* bq = (const float*)d_in[4];
    const float* Wk = (const float*)d_in[5];
    const float* bk = (const float*)d_in[6];
    const float* Wv = (const float*)d_in[7];
    const float* bv = (const float*)d_in[8];
    const float* Wo = (const float*)d_in[9];
    const float* bo = (const float*)d_in[10];

    const int M = 4096, N = 1024, K = 1024;
    const size_t nBS = (size_t)M * N;
    const size_t nW  = (size_t)N * K;

    unsigned short* qb   = (unsigned short*)d_ws;
    unsigned short* kb   = qb  + nBS;
    unsigned short* vb   = kb  + nBS;
    unsigned short* Wqb  = vb  + nBS;
    unsigned short* Wkb  = Wqb + nW;
    unsigned short* Wvb  = Wkb + nW;
    unsigned short* Wob  = Wvb + nW;
    unsigned short* Qp   = Wob + nW;
    unsigned short* Kp   = Qp  + nBS;
    unsigned short* Vp   = Kp  + nBS;
    unsigned short* VpT  = Vp  + nBS;
    unsigned short* Ct   = qb;            // alias: qb dead after QKV GEMM

    dim3 gc(1024, 1, 7);
    conv_bf16<<<gc, 256, 0, stream>>>(q, k, v, Wq, Wk, Wv, Wo,
                                      qb, kb, vb, Wqb, Wkb, Wvb, Wob,
                                      (int)(nBS / 4), (int)(nW / 4));

    dim3 g1(N / 128, M / 128, 3);
    gemm_bf16<true><<<g1, 256, 0, stream>>>(qb, kb, vb, Wqb, Wkb, Wvb,
                                            bq, bk, bv, Qp, Kp, Vp, M, N, K);

    dim3 gt(32, 32);
    transpose_v<<<gt, 256, 0, stream>>>(Vp, VpT);

    dim3 g2(16, 32);
    attn_causal<<<g2, 128, 0, stream>>>(Qp, Kp, VpT, Ct);

    dim3 g3(N / 128, M / 128, 1);
    gemm_bf16<false><<<g3, 256, 0, stream>>>(Ct, Ct, Ct, Wob, Wob, Wob,
                                             bo, bo, bo, d_out, d_out, d_out, M, N, K);
}